// Round 1
// 292.789 us; speedup vs baseline: 1.0205x; 1.0205x over previous
//
#include <hip/hip_runtime.h>

// ROI Align (FPN multi-level), OUT=7, ratio=2. Wave-per-(ROI,channel).
// Round-5: counters showed VALU-bound (74% VALUBusy, 37% HBM, occupancy ok).
// ~2/3 of per-wave VALU was per-ROI-uniform geometry recomputed 256x per ROI
// (level assign w/ sqrt+log2, 28-lane axis weights, 3 runtime int divisions).
// Fix: per-ROI precompute kernel writes a 512B table (staging scalars with
// magic-mul constants replacing all divisions; axis taps pre-folded to
// footprint-relative indices; y-entries pre-multiplied by LDS row pitch,
// packed uint4). Main kernel keeps the async global_load_lds(16) staging,
// zero barriers; compute phase is pure add + ds_read + FMA.
// LDS drops 20.2KB -> 18.4KB/block; still 8 blocks/CU -> 32 waves/CU.

#define NCH 256
#define POOL 7
#define NBIN 49
#define CAP 1152          // floats per wave footprint region (max ~1040)
#define WPB 4             // waves per 256-thread block
#define TS 128            // u32 words per ROI table entry (512 B)

typedef __attribute__((address_space(3))) void       as3_void;
typedef __attribute__((address_space(1))) const void as1_void;

// ---------------------------------------------------------------------------
// Per-ROI precompute: one wave per ROI. Writes tab[m*TS .. m*TS+127]:
//  [0] base_off (elems, c=0)   [1] lvl      [2] HW        [3] W
//  [4] lpr                     [5] Mg=ceil(65536/lpr)     [6] rpi=64/lpr
//  [7] iters                   [8] gstep=rpi*W (elems)    [9] lstepB=rpi*RS4*4
//  [10] (FH-1)*W               [11] safe    [12] FW       [13] RS4
//  [14] FH2 (fallback rows)    [15] Mg2=ceil(2^22/RS4)
//  [16..71]  xtab[14] uint4: {xr, xp=min(xr+1,FW-1), wxl, wxh}   (elems)
//  [72..127] ytab[14] uint4: {(ylo-ry0)*RS4, (yhi-ry0)*RS4, wyl, wyh}
// ---------------------------------------------------------------------------
__global__ __launch_bounds__(256) void roi_precompute_kernel(
    const float* __restrict__ boxes, const int* __restrict__ bidx,
    unsigned int* __restrict__ tab, int M)
{
    const int lane = threadIdx.x & 63;
    const int m = blockIdx.x * WPB + (threadIdx.x >> 6);
    if (m >= M) return;

    float bx0 = boxes[4 * m + 0];
    float by0 = boxes[4 * m + 1];
    float bx1 = boxes[4 * m + 2];
    float by1 = boxes[4 * m + 3];

    float area = (bx1 - bx0) * (by1 - by0);
    float sz   = sqrtf(area);
    float lvlf = floorf(4.0f + log2f(sz / 224.0f + 1e-8f));
    lvlf = fminf(fmaxf(lvlf, 2.0f), 5.0f);
    int lvl = (int)lvlf - 2;

    int H, W; float scale;
    if (lvl == 0)      { H = 200; W = 304; scale = 0.25f;    }
    else if (lvl == 1) { H = 100; W = 152; scale = 0.125f;   }
    else if (lvl == 2) { H = 50;  W = 76;  scale = 0.0625f;  }
    else               { H = 25;  W = 38;  scale = 0.03125f; }

    float x0 = bx0 * scale - 0.5f;
    float y0 = by0 * scale - 0.5f;
    float bin_w = (bx1 * scale - 0.5f - x0) * (1.0f / 7.0f);
    float bin_h = (by1 * scale - 0.5f - y0) * (1.0f / 7.0f);

    // lanes 0..13: x samples; lanes 14..27: y samples (28..63 compute garbage,
    // never read: shfl sources and writes stay within lanes 0..27)
    int axis = lane >= 14;
    int s    = axis ? (lane - 14) : lane;
    float off = (float)(s >> 1) + ((s & 1) ? 0.75f : 0.25f);
    float cv    = axis ? (y0 + bin_h * off) : (x0 + bin_w * off);
    float size  = axis ? (float)H : (float)W;
    float valid = (cv >= -1.0f && cv <= size) ? 1.0f : 0.0f;
    float cc    = fmaxf(cv, 0.0f);
    float lo_f  = floorf(cc);
    bool  capd  = lo_f >= size - 1.0f;
    int   lo    = capd ? (int)size - 1 : (int)lo_f;
    int   hi    = capd ? lo : lo + 1;
    float l     = capd ? 0.0f : (cc - lo_f);
    float wlo   = (1.0f - l) * valid;
    float whi   = l * valid;

    int rx0 = __shfl(lo, 0);
    int rxe = __shfl(hi, 13);
    int ry0 = __shfl(lo, 14);
    int rye = __shfl(hi, 27);

    int FW  = rxe - rx0 + 1;
    int FH  = rye - ry0 + 1;
    int lpr = (FW + 3) >> 2;
    int RS4 = lpr << 2;
    int rpi = 64 / lpr;
    int iters = (FH + rpi - 1) / rpi;
    unsigned Mg  = (65536u   + (unsigned)lpr - 1u) / (unsigned)lpr;
    unsigned Mg2 = (4194304u + (unsigned)RS4 - 1u) / (unsigned)RS4;
    unsigned HW  = (unsigned)(H * W);
    unsigned base_off = (unsigned)bidx[m] * 256u * HW
                      + (unsigned)ry0 * (unsigned)W + (unsigned)rx0;
    int FH2 = FH;
    if (FH2 * RS4 > CAP) FH2 = CAP / RS4;
    // safe for ALL channels iff safe for c=255 (largest offset)
    unsigned lastoff = base_off + 255u * HW
                     + (unsigned)(FH - 1) * (unsigned)W + (unsigned)RS4;
    int safe = (lastoff <= 2u * 256u * HW) && (FH * RS4 <= CAP);

    unsigned* t = tab + (size_t)m * TS;
    if (lane == 0) {
        t[0]  = base_off;
        t[1]  = (unsigned)lvl;
        t[2]  = HW;
        t[3]  = (unsigned)W;
        t[4]  = (unsigned)lpr;
        t[5]  = Mg;
        t[6]  = (unsigned)rpi;
        t[7]  = (unsigned)iters;
        t[8]  = (unsigned)(rpi * W);
        t[9]  = (unsigned)((rpi * RS4) << 2);
        t[10] = (unsigned)((FH - 1) * W);
        t[11] = (unsigned)safe;
        t[12] = (unsigned)FW;
        t[13] = (unsigned)RS4;
        t[14] = (unsigned)FH2;
        t[15] = Mg2;
    }
    if (lane < 28) {
        if (!axis) {
            int xr = lo - rx0;
            int xp = min(xr + 1, FW - 1);   // cap-x: weight is 0, stay in row
            uint4 v;
            v.x = (unsigned)xr;
            v.y = (unsigned)xp;
            v.z = __float_as_uint(wlo);
            v.w = __float_as_uint(whi);
            *(uint4*)(t + 16 + 4 * s) = v;
        } else {
            uint4 v;
            v.x = (unsigned)((lo - ry0) * RS4);
            v.y = (unsigned)((hi - ry0) * RS4);
            v.z = __float_as_uint(wlo);
            v.w = __float_as_uint(whi);
            *(uint4*)(t + 72 + 4 * s) = v;
        }
    }
}

// ---------------------------------------------------------------------------
// Main kernel: wave-per-(ROI,channel), geometry from precomputed table.
// ---------------------------------------------------------------------------
__global__ __launch_bounds__(256, 8) void roi_align_kernel(
    const float* __restrict__ f0, const float* __restrict__ f1,
    const float* __restrict__ f2, const float* __restrict__ f3,
    const unsigned int* __restrict__ tab,
    float* __restrict__ out, int M)
{
    __shared__ float sF[WPB][CAP];

    const int lane = threadIdx.x & 63;
    const int w    = __builtin_amdgcn_readfirstlane(threadIdx.x >> 6);
    const int unit = blockIdx.x * WPB + w;            // (m, c), wave-uniform
    if (unit >= M * NCH) return;
    const int m = unit >> 8;
    const int c = unit & (NCH - 1);

    const unsigned* t = tab + (size_t)m * TS;

    // ---- per-lane geometry (issued early; overlaps staging latency) ----
    const int ci = lane < NBIN ? lane : 0;            // clamp lanes 49..63
    const int py = ci / POOL;                         // const-div -> magic
    const int px = ci - POOL * py;
    const uint4* xt = (const uint4*)(t + 16);
    const uint4* yt = (const uint4*)(t + 72);
    const uint4 X0 = xt[2 * px];
    const uint4 X1 = xt[2 * px + 1];
    const uint4 Y0 = yt[2 * py];
    const uint4 Y1 = yt[2 * py + 1];

    // ---- wave-uniform staging scalars ----
    const uint4 s0 = *(const uint4*)(t);              // base_off, lvl, HW, W
    const uint4 s1 = *(const uint4*)(t + 4);          // lpr, Mg, rpi, iters
    const uint4 s2 = *(const uint4*)(t + 8);          // gstep, lstepB, fhw, safe

    const int lvl = __builtin_amdgcn_readfirstlane((int)s0.y);
    const float* fp = (lvl == 0) ? f0 : (lvl == 1) ? f1 : (lvl == 2) ? f2 : f3;
    const unsigned HW = s0.z;
    const unsigned Wd = s0.w;
    const float* src = fp + (size_t)(s0.x + (unsigned)c * HW);

    const int safe = __builtin_amdgcn_readfirstlane((int)s2.w);
    if (safe) {
        const int lpr      = __builtin_amdgcn_readfirstlane((int)s1.x);
        const unsigned Mg  = s1.y;
        const int rpi      = __builtin_amdgcn_readfirstlane((int)s1.z);
        const int iters    = __builtin_amdgcn_readfirstlane((int)s1.w);
        const unsigned gstep  = s2.x;                 // elems
        const unsigned lstepB = __builtin_amdgcn_readfirstlane((int)s2.y);
        const unsigned fhw    = s2.z;                 // (FH-1)*W elems

        int sfy  = (int)(((unsigned)lane * Mg) >> 16);   // lane / lpr, exact
        int sfx4 = (lane - sfy * lpr) << 2;
        if (sfy < rpi) {
            const float* g    = src + (unsigned)sfy * Wd + (unsigned)sfx4;
            const float* gmax = src + fhw + (unsigned)sfx4;
            char* lb = (char*)&sF[w][0];
            for (int it = 0; it < iters; ++it) {
                const float* gc = (g > gmax) ? gmax : g;   // pad rows reload
                __builtin_amdgcn_global_load_lds((as1_void*)gc,
                                                 (as3_void*)lb, 16, 0, 0);
                g  += gstep;
                lb += lstepB;
            }
        }
    } else {
        // rare tail/oversize fallback: scalar staging, always in-bounds
        const uint4 s3 = *(const uint4*)(t + 12);     // FW, RS4, FH2, Mg2
        const int FW  = __builtin_amdgcn_readfirstlane((int)s3.x);
        const int RS4 = __builtin_amdgcn_readfirstlane((int)s3.y);
        const int FH2 = __builtin_amdgcn_readfirstlane((int)s3.z);
        const unsigned Mg2 = s3.w;
        const int tot = FH2 * RS4;
        for (int i = lane; i < tot; i += 64) {
            int fy = (int)(((unsigned)i * Mg2) >> 22);   // i / RS4, exact
            int fx = i - fy * RS4;
            int cx = fx < FW ? fx : FW - 1;
            sF[w][i] = src[(unsigned)fy * Wd + (unsigned)cx];
        }
    }

    __builtin_amdgcn_s_waitcnt(0);        // drain async LDS fills + table loads
    __asm__ __volatile__("" ::: "memory");

    // ---- compute 49 bins from LDS (lanes 0..48): adds + ds_read + FMA ----
    if (lane < NBIN) {
        const float* Fb = &sF[w][0];
        const unsigned xr0 = X0.x, xp0 = X0.y, xr1 = X1.x, xp1 = X1.y;
        const float wxl0 = __uint_as_float(X0.z), wxh0 = __uint_as_float(X0.w);
        const float wxl1 = __uint_as_float(X1.z), wxh1 = __uint_as_float(X1.w);
        const unsigned ra = Y0.x, rb = Y0.y, rc = Y1.x, rd = Y1.y;

        float a0 = Fb[ra + xr0] * wxl0 + Fb[ra + xp0] * wxh0
                 + Fb[ra + xr1] * wxl1 + Fb[ra + xp1] * wxh1;
        float a1 = Fb[rb + xr0] * wxl0 + Fb[rb + xp0] * wxh0
                 + Fb[rb + xr1] * wxl1 + Fb[rb + xp1] * wxh1;
        float a2 = Fb[rc + xr0] * wxl0 + Fb[rc + xp0] * wxh0
                 + Fb[rc + xr1] * wxl1 + Fb[rc + xp1] * wxh1;
        float a3 = Fb[rd + xr0] * wxl0 + Fb[rd + xp0] * wxh0
                 + Fb[rd + xr1] * wxl1 + Fb[rd + xp1] * wxh1;

        float acc = __uint_as_float(Y0.z) * a0 + __uint_as_float(Y0.w) * a1
                  + __uint_as_float(Y1.z) * a2 + __uint_as_float(Y1.w) * a3;

        out[(size_t)unit * NBIN + lane] = acc * 0.25f;
    }
}

extern "C" void kernel_launch(void* const* d_in, const int* in_sizes, int n_in,
                              void* d_out, int out_size, void* d_ws, size_t ws_size,
                              hipStream_t stream) {
    const float* f0    = (const float*)d_in[0];
    const float* f1    = (const float*)d_in[1];
    const float* f2    = (const float*)d_in[2];
    const float* f3    = (const float*)d_in[3];
    const float* boxes = (const float*)d_in[4];
    const int*   bidx  = (const int*)d_in[5];
    float* out = (float*)d_out;

    int M = in_sizes[4] / 4;
    unsigned int* tab = (unsigned int*)d_ws;          // M * 512 B

    int pblocks = (M + WPB - 1) / WPB;
    hipLaunchKernelGGL(roi_precompute_kernel, dim3(pblocks), dim3(256), 0,
                       stream, boxes, bidx, tab, M);

    int units = M * NCH;
    int blocks = (units + WPB - 1) / WPB;
    hipLaunchKernelGGL(roi_align_kernel, dim3(blocks), dim3(256), 0, stream,
                       f0, f1, f2, f3, tab, out, M);
}

// Round 2
// 281.217 us; speedup vs baseline: 1.0624x; 1.0411x over previous
//
#include <hip/hip_runtime.h>

// ROI Align (FPN multi-level), OUT=7, ratio=2. Wave-per-(ROI,channel).
// Round-6: counters showed latency-bound (VALU 23%, HBM 40%, occ 79% — no
// pipe saturated). FETCH=356MB >> 165MB unique feature bytes: m-major unit
// order gives zero locality, every footprint is a cold ~900cy HBM miss that
// each short-lived wave eats serially. Fix: c-major ordering with XCD channel
// chunking — each XCD owns 32 channels and sweeps all ROIs within a channel;
// a channel-plane (~1.3MB all levels+batches) and the ROI tables (512KB)
// become L2-resident, turning staging reads into ~200cy L2 hits and dropping
// HBM fetch to the compulsory ~165MB. Kernels otherwise unchanged:
// per-ROI precomputed geometry table + async global_load_lds(16) staging,
// zero barriers; 18.4KB LDS/block -> 8 blocks/CU -> 32 waves/CU.

#define NCH 256
#define POOL 7
#define NBIN 49
#define CAP 1152          // floats per wave footprint region (max ~1040)
#define WPB 4             // waves per 256-thread block
#define TS 128            // u32 words per ROI table entry (512 B)

typedef __attribute__((address_space(3))) void       as3_void;
typedef __attribute__((address_space(1))) const void as1_void;

// ---------------------------------------------------------------------------
// Per-ROI precompute: one wave per ROI. Writes tab[m*TS .. m*TS+127]:
//  [0] base_off (elems, c=0)   [1] lvl      [2] HW        [3] W
//  [4] lpr                     [5] Mg=ceil(65536/lpr)     [6] rpi=64/lpr
//  [7] iters                   [8] gstep=rpi*W (elems)    [9] lstepB=rpi*RS4*4
//  [10] (FH-1)*W               [11] safe    [12] FW       [13] RS4
//  [14] FH2 (fallback rows)    [15] Mg2=ceil(2^22/RS4)
//  [16..71]  xtab[14] uint4: {xr, xp=min(xr+1,FW-1), wxl, wxh}   (elems)
//  [72..127] ytab[14] uint4: {(ylo-ry0)*RS4, (yhi-ry0)*RS4, wyl, wyh}
// ---------------------------------------------------------------------------
__global__ __launch_bounds__(256) void roi_precompute_kernel(
    const float* __restrict__ boxes, const int* __restrict__ bidx,
    unsigned int* __restrict__ tab, int M)
{
    const int lane = threadIdx.x & 63;
    const int m = blockIdx.x * WPB + (threadIdx.x >> 6);
    if (m >= M) return;

    float bx0 = boxes[4 * m + 0];
    float by0 = boxes[4 * m + 1];
    float bx1 = boxes[4 * m + 2];
    float by1 = boxes[4 * m + 3];

    float area = (bx1 - bx0) * (by1 - by0);
    float sz   = sqrtf(area);
    float lvlf = floorf(4.0f + log2f(sz / 224.0f + 1e-8f));
    lvlf = fminf(fmaxf(lvlf, 2.0f), 5.0f);
    int lvl = (int)lvlf - 2;

    int H, W; float scale;
    if (lvl == 0)      { H = 200; W = 304; scale = 0.25f;    }
    else if (lvl == 1) { H = 100; W = 152; scale = 0.125f;   }
    else if (lvl == 2) { H = 50;  W = 76;  scale = 0.0625f;  }
    else               { H = 25;  W = 38;  scale = 0.03125f; }

    float x0 = bx0 * scale - 0.5f;
    float y0 = by0 * scale - 0.5f;
    float bin_w = (bx1 * scale - 0.5f - x0) * (1.0f / 7.0f);
    float bin_h = (by1 * scale - 0.5f - y0) * (1.0f / 7.0f);

    // lanes 0..13: x samples; lanes 14..27: y samples (28..63 compute garbage,
    // never read: shfl sources and writes stay within lanes 0..27)
    int axis = lane >= 14;
    int s    = axis ? (lane - 14) : lane;
    float off = (float)(s >> 1) + ((s & 1) ? 0.75f : 0.25f);
    float cv    = axis ? (y0 + bin_h * off) : (x0 + bin_w * off);
    float size  = axis ? (float)H : (float)W;
    float valid = (cv >= -1.0f && cv <= size) ? 1.0f : 0.0f;
    float cc    = fmaxf(cv, 0.0f);
    float lo_f  = floorf(cc);
    bool  capd  = lo_f >= size - 1.0f;
    int   lo    = capd ? (int)size - 1 : (int)lo_f;
    int   hi    = capd ? lo : lo + 1;
    float l     = capd ? 0.0f : (cc - lo_f);
    float wlo   = (1.0f - l) * valid;
    float whi   = l * valid;

    int rx0 = __shfl(lo, 0);
    int rxe = __shfl(hi, 13);
    int ry0 = __shfl(lo, 14);
    int rye = __shfl(hi, 27);

    int FW  = rxe - rx0 + 1;
    int FH  = rye - ry0 + 1;
    int lpr = (FW + 3) >> 2;
    int RS4 = lpr << 2;
    int rpi = 64 / lpr;
    int iters = (FH + rpi - 1) / rpi;
    unsigned Mg  = (65536u   + (unsigned)lpr - 1u) / (unsigned)lpr;
    unsigned Mg2 = (4194304u + (unsigned)RS4 - 1u) / (unsigned)RS4;
    unsigned HW  = (unsigned)(H * W);
    unsigned base_off = (unsigned)bidx[m] * 256u * HW
                      + (unsigned)ry0 * (unsigned)W + (unsigned)rx0;
    int FH2 = FH;
    if (FH2 * RS4 > CAP) FH2 = CAP / RS4;
    // safe for ALL channels iff safe for c=255 (largest offset)
    unsigned lastoff = base_off + 255u * HW
                     + (unsigned)(FH - 1) * (unsigned)W + (unsigned)RS4;
    int safe = (lastoff <= 2u * 256u * HW) && (FH * RS4 <= CAP);

    unsigned* t = tab + (size_t)m * TS;
    if (lane == 0) {
        t[0]  = base_off;
        t[1]  = (unsigned)lvl;
        t[2]  = HW;
        t[3]  = (unsigned)W;
        t[4]  = (unsigned)lpr;
        t[5]  = Mg;
        t[6]  = (unsigned)rpi;
        t[7]  = (unsigned)iters;
        t[8]  = (unsigned)(rpi * W);
        t[9]  = (unsigned)((rpi * RS4) << 2);
        t[10] = (unsigned)((FH - 1) * W);
        t[11] = (unsigned)safe;
        t[12] = (unsigned)FW;
        t[13] = (unsigned)RS4;
        t[14] = (unsigned)FH2;
        t[15] = Mg2;
    }
    if (lane < 28) {
        if (!axis) {
            int xr = lo - rx0;
            int xp = min(xr + 1, FW - 1);   // cap-x: weight is 0, stay in row
            uint4 v;
            v.x = (unsigned)xr;
            v.y = (unsigned)xp;
            v.z = __float_as_uint(wlo);
            v.w = __float_as_uint(whi);
            *(uint4*)(t + 16 + 4 * s) = v;
        } else {
            uint4 v;
            v.x = (unsigned)((lo - ry0) * RS4);
            v.y = (unsigned)((hi - ry0) * RS4);
            v.z = __float_as_uint(wlo);
            v.w = __float_as_uint(whi);
            *(uint4*)(t + 72 + 4 * s) = v;
        }
    }
}

// ---------------------------------------------------------------------------
// Main kernel: wave-per-(ROI,channel), c-major order, XCD channel chunking.
// Block remap: raw block b -> xcd = b&7 owns channels [xcd*32, xcd*32+32);
// within an XCD, blocks sweep all M ROIs of one channel before advancing.
// ---------------------------------------------------------------------------
__global__ __launch_bounds__(256, 8) void roi_align_kernel(
    const float* __restrict__ f0, const float* __restrict__ f1,
    const float* __restrict__ f2, const float* __restrict__ f3,
    const unsigned int* __restrict__ tab,
    float* __restrict__ out, int M)
{
    __shared__ float sF[WPB][CAP];

    const int lane = threadIdx.x & 63;
    const int w    = __builtin_amdgcn_readfirstlane(threadIdx.x >> 6);

    // grid = mblocks * 256 blocks (divisible by 8 since NCH=256)
    const unsigned mblocks = (unsigned)gridDim.x >> 8;
    const unsigned rb   = blockIdx.x;
    const unsigned xcd  = rb & 7u;
    const unsigned idx  = rb >> 3;                 // 0 .. mblocks*32-1
    const unsigned cblk = idx / mblocks;           // 0..31 (once per block)
    const unsigned mb   = idx - cblk * mblocks;
    const int c = (int)(xcd * 32u + cblk);
    const int m = (int)(mb * WPB) + w;
    if (m >= M) return;
    const int unit = m * NCH + c;                  // output index (m-major)

    const unsigned* t = tab + (size_t)m * TS;

    // ---- per-lane geometry (issued early; overlaps staging latency) ----
    const int ci = lane < NBIN ? lane : 0;         // clamp lanes 49..63
    const int py = ci / POOL;                      // const-div -> magic
    const int px = ci - POOL * py;
    const uint4* xt = (const uint4*)(t + 16);
    const uint4* yt = (const uint4*)(t + 72);
    const uint4 X0 = xt[2 * px];
    const uint4 X1 = xt[2 * px + 1];
    const uint4 Y0 = yt[2 * py];
    const uint4 Y1 = yt[2 * py + 1];

    // ---- wave-uniform staging scalars ----
    const uint4 s0 = *(const uint4*)(t);           // base_off, lvl, HW, W
    const uint4 s1 = *(const uint4*)(t + 4);       // lpr, Mg, rpi, iters
    const uint4 s2 = *(const uint4*)(t + 8);       // gstep, lstepB, fhw, safe

    const int lvl = __builtin_amdgcn_readfirstlane((int)s0.y);
    const float* fp = (lvl == 0) ? f0 : (lvl == 1) ? f1 : (lvl == 2) ? f2 : f3;
    const unsigned HW = s0.z;
    const unsigned Wd = s0.w;
    const float* src = fp + (size_t)(s0.x + (unsigned)c * HW);

    const int safe = __builtin_amdgcn_readfirstlane((int)s2.w);
    if (safe) {
        const int lpr      = __builtin_amdgcn_readfirstlane((int)s1.x);
        const unsigned Mg  = s1.y;
        const int rpi      = __builtin_amdgcn_readfirstlane((int)s1.z);
        const int iters    = __builtin_amdgcn_readfirstlane((int)s1.w);
        const unsigned gstep  = s2.x;              // elems
        const unsigned lstepB = __builtin_amdgcn_readfirstlane((int)s2.y);
        const unsigned fhw    = s2.z;              // (FH-1)*W elems

        int sfy  = (int)(((unsigned)lane * Mg) >> 16);   // lane / lpr, exact
        int sfx4 = (lane - sfy * lpr) << 2;
        if (sfy < rpi) {
            const float* g    = src + (unsigned)sfy * Wd + (unsigned)sfx4;
            const float* gmax = src + fhw + (unsigned)sfx4;
            char* lb = (char*)&sF[w][0];
            for (int it = 0; it < iters; ++it) {
                const float* gc = (g > gmax) ? gmax : g;   // pad rows reload
                __builtin_amdgcn_global_load_lds((as1_void*)gc,
                                                 (as3_void*)lb, 16, 0, 0);
                g  += gstep;
                lb += lstepB;
            }
        }
    } else {
        // rare tail/oversize fallback: scalar staging, always in-bounds
        const uint4 s3 = *(const uint4*)(t + 12);  // FW, RS4, FH2, Mg2
        const int FW  = __builtin_amdgcn_readfirstlane((int)s3.x);
        const int RS4 = __builtin_amdgcn_readfirstlane((int)s3.y);
        const int FH2 = __builtin_amdgcn_readfirstlane((int)s3.z);
        const unsigned Mg2 = s3.w;
        const int tot = FH2 * RS4;
        for (int i = lane; i < tot; i += 64) {
            int fy = (int)(((unsigned)i * Mg2) >> 22);   // i / RS4, exact
            int fx = i - fy * RS4;
            int cx = fx < FW ? fx : FW - 1;
            sF[w][i] = src[(unsigned)fy * Wd + (unsigned)cx];
        }
    }

    __builtin_amdgcn_s_waitcnt(0);        // drain async LDS fills + table loads
    __asm__ __volatile__("" ::: "memory");

    // ---- compute 49 bins from LDS (lanes 0..48): adds + ds_read + FMA ----
    if (lane < NBIN) {
        const float* Fb = &sF[w][0];
        const unsigned xr0 = X0.x, xp0 = X0.y, xr1 = X1.x, xp1 = X1.y;
        const float wxl0 = __uint_as_float(X0.z), wxh0 = __uint_as_float(X0.w);
        const float wxl1 = __uint_as_float(X1.z), wxh1 = __uint_as_float(X1.w);
        const unsigned ra = Y0.x, rb2 = Y0.y, rc = Y1.x, rd = Y1.y;

        float a0 = Fb[ra + xr0] * wxl0 + Fb[ra + xp0] * wxh0
                 + Fb[ra + xr1] * wxl1 + Fb[ra + xp1] * wxh1;
        float a1 = Fb[rb2 + xr0] * wxl0 + Fb[rb2 + xp0] * wxh0
                 + Fb[rb2 + xr1] * wxl1 + Fb[rb2 + xp1] * wxh1;
        float a2 = Fb[rc + xr0] * wxl0 + Fb[rc + xp0] * wxh0
                 + Fb[rc + xr1] * wxl1 + Fb[rc + xp1] * wxh1;
        float a3 = Fb[rd + xr0] * wxl0 + Fb[rd + xp0] * wxh0
                 + Fb[rd + xr1] * wxl1 + Fb[rd + xp1] * wxh1;

        float acc = __uint_as_float(Y0.z) * a0 + __uint_as_float(Y0.w) * a1
                  + __uint_as_float(Y1.z) * a2 + __uint_as_float(Y1.w) * a3;

        out[(size_t)unit * NBIN + lane] = acc * 0.25f;
    }
}

extern "C" void kernel_launch(void* const* d_in, const int* in_sizes, int n_in,
                              void* d_out, int out_size, void* d_ws, size_t ws_size,
                              hipStream_t stream) {
    const float* f0    = (const float*)d_in[0];
    const float* f1    = (const float*)d_in[1];
    const float* f2    = (const float*)d_in[2];
    const float* f3    = (const float*)d_in[3];
    const float* boxes = (const float*)d_in[4];
    const int*   bidx  = (const int*)d_in[5];
    float* out = (float*)d_out;

    int M = in_sizes[4] / 4;
    unsigned int* tab = (unsigned int*)d_ws;          // M * 512 B

    int pblocks = (M + WPB - 1) / WPB;
    hipLaunchKernelGGL(roi_precompute_kernel, dim3(pblocks), dim3(256), 0,
                       stream, boxes, bidx, tab, M);

    int mblocks = (M + WPB - 1) / WPB;
    int blocks = mblocks * NCH;
    hipLaunchKernelGGL(roi_align_kernel, dim3(blocks), dim3(256), 0, stream,
                       f0, f1, f2, f3, tab, out, M);
}

// Round 3
// 276.034 us; speedup vs baseline: 1.0824x; 1.0188x over previous
//
#include <hip/hip_runtime.h>

// ROI Align (FPN multi-level), OUT=7, ratio=2.
// Round-7: counters showed pure latency-bound (VALU 28%, HBM 14%, occ 77%).
// Wave lifetime ~7200cy, only ~320cy busy: each 1-unit wave pays the full
// serial chain (table L2 RT -> staging flight -> waitcnt tail -> ds_read)
// for 196B of output. Fix: 2 channels of the SAME ROI per wave — one table
// read, one geometry register set, both footprints' global_load_lds in one
// combined flight, one waitcnt, two LDS compute phases. Waves halve (128K),
// sequential rounds/CU drop 40.6 -> 31.25, chain amortized over 2 units.
// LDS 36.9KB/block -> 4 blocks/CU -> 16 waves/CU (accepted: latency chain
// amortization beats the lost concurrency). c-major XCD channel chunking
// retained (FETCH stays ~77MB, L2/L3-resident reads).

#define NCH 256
#define POOL 7
#define NBIN 49
#define CAP 1152          // floats per unit footprint region (max ~1040)
#define WPB 4             // waves per 256-thread block
#define TS 128            // u32 words per ROI table entry (512 B)

typedef __attribute__((address_space(3))) void       as3_void;
typedef __attribute__((address_space(1))) const void as1_void;

// ---------------------------------------------------------------------------
// Per-ROI precompute: one wave per ROI. Writes tab[m*TS .. m*TS+127]:
//  [0] base_off (elems, c=0)   [1] lvl      [2] HW        [3] W
//  [4] lpr                     [5] Mg=ceil(65536/lpr)     [6] rpi=64/lpr
//  [7] iters                   [8] gstep=rpi*W (elems)    [9] lstepB=rpi*RS4*4
//  [10] (FH-1)*W               [11] safe    [12] FW       [13] RS4
//  [14] FH2 (fallback rows)    [15] Mg2=ceil(2^22/RS4)
//  [16..71]  xtab[14] uint4: {xr, xp=min(xr+1,FW-1), wxl, wxh}   (elems)
//  [72..127] ytab[14] uint4: {(ylo-ry0)*RS4, (yhi-ry0)*RS4, wyl, wyh}
// ---------------------------------------------------------------------------
__global__ __launch_bounds__(256) void roi_precompute_kernel(
    const float* __restrict__ boxes, const int* __restrict__ bidx,
    unsigned int* __restrict__ tab, int M)
{
    const int lane = threadIdx.x & 63;
    const int m = blockIdx.x * WPB + (threadIdx.x >> 6);
    if (m >= M) return;

    float bx0 = boxes[4 * m + 0];
    float by0 = boxes[4 * m + 1];
    float bx1 = boxes[4 * m + 2];
    float by1 = boxes[4 * m + 3];

    float area = (bx1 - bx0) * (by1 - by0);
    float sz   = sqrtf(area);
    float lvlf = floorf(4.0f + log2f(sz / 224.0f + 1e-8f));
    lvlf = fminf(fmaxf(lvlf, 2.0f), 5.0f);
    int lvl = (int)lvlf - 2;

    int H, W; float scale;
    if (lvl == 0)      { H = 200; W = 304; scale = 0.25f;    }
    else if (lvl == 1) { H = 100; W = 152; scale = 0.125f;   }
    else if (lvl == 2) { H = 50;  W = 76;  scale = 0.0625f;  }
    else               { H = 25;  W = 38;  scale = 0.03125f; }

    float x0 = bx0 * scale - 0.5f;
    float y0 = by0 * scale - 0.5f;
    float bin_w = (bx1 * scale - 0.5f - x0) * (1.0f / 7.0f);
    float bin_h = (by1 * scale - 0.5f - y0) * (1.0f / 7.0f);

    // lanes 0..13: x samples; lanes 14..27: y samples (28..63 compute garbage,
    // never read: shfl sources and writes stay within lanes 0..27)
    int axis = lane >= 14;
    int s    = axis ? (lane - 14) : lane;
    float off = (float)(s >> 1) + ((s & 1) ? 0.75f : 0.25f);
    float cv    = axis ? (y0 + bin_h * off) : (x0 + bin_w * off);
    float size  = axis ? (float)H : (float)W;
    float valid = (cv >= -1.0f && cv <= size) ? 1.0f : 0.0f;
    float cc    = fmaxf(cv, 0.0f);
    float lo_f  = floorf(cc);
    bool  capd  = lo_f >= size - 1.0f;
    int   lo    = capd ? (int)size - 1 : (int)lo_f;
    int   hi    = capd ? lo : lo + 1;
    float l     = capd ? 0.0f : (cc - lo_f);
    float wlo   = (1.0f - l) * valid;
    float whi   = l * valid;

    int rx0 = __shfl(lo, 0);
    int rxe = __shfl(hi, 13);
    int ry0 = __shfl(lo, 14);
    int rye = __shfl(hi, 27);

    int FW  = rxe - rx0 + 1;
    int FH  = rye - ry0 + 1;
    int lpr = (FW + 3) >> 2;
    int RS4 = lpr << 2;
    int rpi = 64 / lpr;
    int iters = (FH + rpi - 1) / rpi;
    unsigned Mg  = (65536u   + (unsigned)lpr - 1u) / (unsigned)lpr;
    unsigned Mg2 = (4194304u + (unsigned)RS4 - 1u) / (unsigned)RS4;
    unsigned HW  = (unsigned)(H * W);
    unsigned base_off = (unsigned)bidx[m] * 256u * HW
                      + (unsigned)ry0 * (unsigned)W + (unsigned)rx0;
    int FH2 = FH;
    if (FH2 * RS4 > CAP) FH2 = CAP / RS4;
    // safe for ALL channels iff safe for c=255 (largest offset)
    unsigned lastoff = base_off + 255u * HW
                     + (unsigned)(FH - 1) * (unsigned)W + (unsigned)RS4;
    int safe = (lastoff <= 2u * 256u * HW) && (FH * RS4 <= CAP);

    unsigned* t = tab + (size_t)m * TS;
    if (lane == 0) {
        t[0]  = base_off;
        t[1]  = (unsigned)lvl;
        t[2]  = HW;
        t[3]  = (unsigned)W;
        t[4]  = (unsigned)lpr;
        t[5]  = Mg;
        t[6]  = (unsigned)rpi;
        t[7]  = (unsigned)iters;
        t[8]  = (unsigned)(rpi * W);
        t[9]  = (unsigned)((rpi * RS4) << 2);
        t[10] = (unsigned)((FH - 1) * W);
        t[11] = (unsigned)safe;
        t[12] = (unsigned)FW;
        t[13] = (unsigned)RS4;
        t[14] = (unsigned)FH2;
        t[15] = Mg2;
    }
    if (lane < 28) {
        if (!axis) {
            int xr = lo - rx0;
            int xp = min(xr + 1, FW - 1);   // cap-x: weight is 0, stay in row
            uint4 v;
            v.x = (unsigned)xr;
            v.y = (unsigned)xp;
            v.z = __float_as_uint(wlo);
            v.w = __float_as_uint(whi);
            *(uint4*)(t + 16 + 4 * s) = v;
        } else {
            uint4 v;
            v.x = (unsigned)((lo - ry0) * RS4);
            v.y = (unsigned)((hi - ry0) * RS4);
            v.z = __float_as_uint(wlo);
            v.w = __float_as_uint(whi);
            *(uint4*)(t + 72 + 4 * s) = v;
        }
    }
}

// ---------------------------------------------------------------------------
// Main kernel: 2 channels of one ROI per wave, c-major, XCD channel chunking.
// Block remap: raw block b -> xcd = b&7 owns channel-pairs [xcd*16,xcd*16+16);
// within an XCD, blocks sweep all M ROIs of one pair before advancing.
// ---------------------------------------------------------------------------
__global__ __launch_bounds__(256, 4) void roi_align_kernel(
    const float* __restrict__ f0, const float* __restrict__ f1,
    const float* __restrict__ f2, const float* __restrict__ f3,
    const unsigned int* __restrict__ tab,
    float* __restrict__ out, int M)
{
    __shared__ float sF[WPB][2 * CAP];

    const int lane = threadIdx.x & 63;
    const int w    = __builtin_amdgcn_readfirstlane(threadIdx.x >> 6);

    // grid = mblocks * 128 blocks (divisible by 8)
    const unsigned mblocks = (unsigned)gridDim.x >> 7;
    const unsigned rb    = blockIdx.x;
    const unsigned xcd   = rb & 7u;
    const unsigned idx   = rb >> 3;                // 0 .. mblocks*16-1
    const unsigned cpblk = idx / mblocks;          // 0..15 (once per block)
    const unsigned mb    = idx - cpblk * mblocks;
    const int c0 = (int)((xcd * 16u + cpblk) * 2u);   // even channel of pair
    const int m  = (int)(mb * WPB) + w;
    if (m >= M) return;

    const unsigned* t = tab + (size_t)m * TS;

    // ---- per-lane geometry: shared by both units (same ROI) ----
    const int ci = lane < NBIN ? lane : 0;         // clamp lanes 49..63
    const int py = ci / POOL;                      // const-div -> magic
    const int px = ci - POOL * py;
    const uint4* xt = (const uint4*)(t + 16);
    const uint4* yt = (const uint4*)(t + 72);
    const uint4 X0 = xt[2 * px];
    const uint4 X1 = xt[2 * px + 1];
    const uint4 Y0 = yt[2 * py];
    const uint4 Y1 = yt[2 * py + 1];

    // ---- wave-uniform staging scalars ----
    const uint4 s0 = *(const uint4*)(t);           // base_off, lvl, HW, W
    const uint4 s1 = *(const uint4*)(t + 4);       // lpr, Mg, rpi, iters
    const uint4 s2 = *(const uint4*)(t + 8);       // gstep, lstepB, fhw, safe

    const int lvl = __builtin_amdgcn_readfirstlane((int)s0.y);
    const float* fp = (lvl == 0) ? f0 : (lvl == 1) ? f1 : (lvl == 2) ? f2 : f3;
    const unsigned HW = s0.z;
    const unsigned Wd = s0.w;
    const float* srcA = fp + (size_t)(s0.x + (unsigned)c0 * HW);
    const float* srcB = srcA + HW;

    const int safe = __builtin_amdgcn_readfirstlane((int)s2.w);
    if (safe) {
        const int lpr      = __builtin_amdgcn_readfirstlane((int)s1.x);
        const unsigned Mg  = s1.y;
        const int rpi      = __builtin_amdgcn_readfirstlane((int)s1.z);
        const int iters    = __builtin_amdgcn_readfirstlane((int)s1.w);
        const unsigned gstep  = s2.x;              // elems
        const unsigned lstepB = __builtin_amdgcn_readfirstlane((int)s2.y);
        const unsigned fhw    = s2.z;              // (FH-1)*W elems

        int sfy  = (int)(((unsigned)lane * Mg) >> 16);   // lane / lpr, exact
        int sfx4 = (lane - sfy * lpr) << 2;
        if (sfy < rpi) {
            const float* gA    = srcA + (unsigned)sfy * Wd + (unsigned)sfx4;
            const float* gmaxA = srcA + fhw + (unsigned)sfx4;
            const float* gB    = srcB + (unsigned)sfy * Wd + (unsigned)sfx4;
            const float* gmaxB = srcB + fhw + (unsigned)sfx4;
            char* lbA = (char*)&sF[w][0];
            char* lbB = (char*)&sF[w][CAP];
            // both units' flights fully overlapped; single drain below
            for (int it = 0; it < iters; ++it) {
                const float* gcA = (gA > gmaxA) ? gmaxA : gA;  // pad rows reload
                const float* gcB = (gB > gmaxB) ? gmaxB : gB;
                __builtin_amdgcn_global_load_lds((as1_void*)gcA,
                                                 (as3_void*)lbA, 16, 0, 0);
                __builtin_amdgcn_global_load_lds((as1_void*)gcB,
                                                 (as3_void*)lbB, 16, 0, 0);
                gA += gstep; gB += gstep;
                lbA += lstepB; lbB += lstepB;
            }
        }
    } else {
        // rare tail/oversize fallback: scalar staging, always in-bounds
        const uint4 s3 = *(const uint4*)(t + 12);  // FW, RS4, FH2, Mg2
        const int FW  = __builtin_amdgcn_readfirstlane((int)s3.x);
        const int RS4 = __builtin_amdgcn_readfirstlane((int)s3.y);
        const int FH2 = __builtin_amdgcn_readfirstlane((int)s3.z);
        const unsigned Mg2 = s3.w;
        const int tot = FH2 * RS4;
        for (int i = lane; i < tot; i += 64) {
            int fy = (int)(((unsigned)i * Mg2) >> 22);   // i / RS4, exact
            int fx = i - fy * RS4;
            int cx = fx < FW ? fx : FW - 1;
            unsigned goff = (unsigned)fy * Wd + (unsigned)cx;
            sF[w][i]       = srcA[goff];
            sF[w][CAP + i] = srcB[goff];
        }
    }

    __builtin_amdgcn_s_waitcnt(0);        // drain async LDS fills + table loads
    __asm__ __volatile__("" ::: "memory");

    // ---- compute 49 bins x 2 units from LDS (lanes 0..48) ----
    if (lane < NBIN) {
        const float* FbA = &sF[w][0];
        const float* FbB = &sF[w][CAP];
        const unsigned xr0 = X0.x, xp0 = X0.y, xr1 = X1.x, xp1 = X1.y;
        const float wxl0 = __uint_as_float(X0.z), wxh0 = __uint_as_float(X0.w);
        const float wxl1 = __uint_as_float(X1.z), wxh1 = __uint_as_float(X1.w);
        const unsigned ra = Y0.x, rb2 = Y0.y, rc = Y1.x, rd = Y1.y;
        const float wy0 = __uint_as_float(Y0.z), wy1 = __uint_as_float(Y0.w);
        const float wy2 = __uint_as_float(Y1.z), wy3 = __uint_as_float(Y1.w);

        float a0 = FbA[ra + xr0] * wxl0 + FbA[ra + xp0] * wxh0
                 + FbA[ra + xr1] * wxl1 + FbA[ra + xp1] * wxh1;
        float a1 = FbA[rb2 + xr0] * wxl0 + FbA[rb2 + xp0] * wxh0
                 + FbA[rb2 + xr1] * wxl1 + FbA[rb2 + xp1] * wxh1;
        float a2 = FbA[rc + xr0] * wxl0 + FbA[rc + xp0] * wxh0
                 + FbA[rc + xr1] * wxl1 + FbA[rc + xp1] * wxh1;
        float a3 = FbA[rd + xr0] * wxl0 + FbA[rd + xp0] * wxh0
                 + FbA[rd + xr1] * wxl1 + FbA[rd + xp1] * wxh1;
        float accA = wy0 * a0 + wy1 * a1 + wy2 * a2 + wy3 * a3;

        float b0 = FbB[ra + xr0] * wxl0 + FbB[ra + xp0] * wxh0
                 + FbB[ra + xr1] * wxl1 + FbB[ra + xp1] * wxh1;
        float b1 = FbB[rb2 + xr0] * wxl0 + FbB[rb2 + xp0] * wxh0
                 + FbB[rb2 + xr1] * wxl1 + FbB[rb2 + xp1] * wxh1;
        float b2 = FbB[rc + xr0] * wxl0 + FbB[rc + xp0] * wxh0
                 + FbB[rc + xr1] * wxl1 + FbB[rc + xp1] * wxh1;
        float b3 = FbB[rd + xr0] * wxl0 + FbB[rd + xp0] * wxh0
                 + FbB[rd + xr1] * wxl1 + FbB[rd + xp1] * wxh1;
        float accB = wy0 * b0 + wy1 * b1 + wy2 * b2 + wy3 * b3;

        size_t ob = ((size_t)m * NCH + (unsigned)c0) * NBIN + (unsigned)lane;
        out[ob]        = accA * 0.25f;
        out[ob + NBIN] = accB * 0.25f;
    }
}

extern "C" void kernel_launch(void* const* d_in, const int* in_sizes, int n_in,
                              void* d_out, int out_size, void* d_ws, size_t ws_size,
                              hipStream_t stream) {
    const float* f0    = (const float*)d_in[0];
    const float* f1    = (const float*)d_in[1];
    const float* f2    = (const float*)d_in[2];
    const float* f3    = (const float*)d_in[3];
    const float* boxes = (const float*)d_in[4];
    const int*   bidx  = (const int*)d_in[5];
    float* out = (float*)d_out;

    int M = in_sizes[4] / 4;
    unsigned int* tab = (unsigned int*)d_ws;          // M * 512 B

    int pblocks = (M + WPB - 1) / WPB;
    hipLaunchKernelGGL(roi_precompute_kernel, dim3(pblocks), dim3(256), 0,
                       stream, boxes, bidx, tab, M);

    int mblocks = (M + WPB - 1) / WPB;
    int blocks = mblocks * (NCH / 2);                 // 2 channels per wave
    hipLaunchKernelGGL(roi_align_kernel, dim3(blocks), dim3(256), 0, stream,
                       f0, f1, f2, f3, tab, out, M);
}